// Round 2
// baseline (449.320 us; speedup 1.0000x reference)
//
#include <hip/hip_runtime.h>
#include <hip/hip_bf16.h>

#define NTOK 49
#define CC   128
#define HDIM 32
#define NHEADS 4
#define HWW  56
#define HW2  3136
#define SCALE_F 0.17677669529663687f

typedef __attribute__((ext_vector_type(8))) short s16x8;
typedef __attribute__((ext_vector_type(4))) float f32x4;

static __device__ __forceinline__ unsigned short f2bf(float f) {
  unsigned int u = __float_as_uint(f);
  u += 0x7fffu + ((u >> 16) & 1u);
  return (unsigned short)(u >> 16);
}
static __device__ __forceinline__ float bf2f(unsigned short h) {
  return __uint_as_float(((unsigned int)h) << 16);
}
// XOR swizzle on u16 index within a row: flips byte bits 4..6 -> keeps 16B alignment
static __device__ __forceinline__ int swzi(int row, int col) {
  return col ^ ((row & 7) << 3);
}

__global__ void wconv_kernel(const float* __restrict__ Wq, const float* __restrict__ Wk,
                             const float* __restrict__ Wv, const float* __restrict__ Wo,
                             unsigned short* __restrict__ dst) {
  int i = blockIdx.x * 256 + threadIdx.x;
  const float* src = (i < 16384) ? Wq : (i < 32768) ? Wk : (i < 49152) ? Wv : Wo;
  dst[i] = f2bf(src[i & 16383]);
}

__global__ __launch_bounds__(256, 2)
void winattn_kernel(const float* __restrict__ Xq, const float* __restrict__ Xk,
                    const float* __restrict__ Xv,
                    const unsigned short* __restrict__ Wbf,
                    const float* __restrict__ bq, const float* __restrict__ bk,
                    const float* __restrict__ bv, const float* __restrict__ bo,
                    const float* __restrict__ rpb,
                    float* __restrict__ out_x,
                    float* __restrict__ out_ctx)
{
  __shared__ alignas(16) unsigned char smem[75200];
  unsigned short* XS = (unsigned short*)smem;          // [49][128] bf16, swizzled (staging, later attn-out)
  unsigned short* Qs = XS + NTOK*CC;                   // [49][128]
  unsigned short* Ks = Qs + NTOK*CC;                   // [49][128]
  unsigned short* VT = Ks + NTOK*CC;                   // [4][32][64]  v transposed per head, tok-swizzled by d
  unsigned short* PB = VT + NHEADS*HDIM*64;            // [64][64] unnormalized softmax probs (bf16, swizzled)
  float* Sm   = (float*)(PB + 64*64);                  // [49][65] fp32 scores
  float* SUMS = Sm + NTOK*65;                          // [49] 1/rowsum

  const int tid = threadIdx.x;
  const int wv  = tid >> 6;
  const int l   = tid & 63;
  const int lr  = l & 15;   // MFMA lane row/col
  const int lg  = l >> 4;   // MFMA k-group

  const int win  = blockIdx.x;
  const int bimg = win >> 6;
  const int r0   = ((win >> 3) & 7) * 7;
  const int c0   = (win & 7) * 7;

  { // zero VT + PB (K-dim padding must be exact zeros; PB pad rows stay zero too)
    unsigned int* z = (unsigned int*)VT;
    for (int i = tid; i < 6144; i += 256) z[i] = 0u;
  }
  __syncthreads();

  auto stage = [&](const float* __restrict__ src) {
    int s = tid & 63, g = tid >> 6;
    if (s < NTOK) {
      int si = s / 7, sj = s - si*7;
      const float* p = src + (size_t)bimg*CC*HW2 + (size_t)(r0+si)*HWW + (c0+sj);
      int base = s * CC;
      #pragma unroll 8
      for (int cc = 0; cc < 32; ++cc) {
        int ci = g*32 + cc;
        XS[base + swzi(s, ci)] = f2bf(p[(size_t)ci * HW2]);
      }
    }
  };

  // D = XS[49x128] * W^T + bias ; W row-major [co][ci] bf16; per-wave: cols 32*wv..32*wv+31
  auto proj = [&](const unsigned short* __restrict__ Wg, const float* __restrict__ bias,
                  unsigned short* __restrict__ dst, int toVT) {
    s16x8 bfr[2][4];
    float bb[2];
    #pragma unroll
    for (int ntl = 0; ntl < 2; ++ntl) {
      int col = wv*32 + ntl*16 + lr;
      bb[ntl] = bias[col];
      #pragma unroll
      for (int ks = 0; ks < 4; ++ks)
        bfr[ntl][ks] = *(const s16x8*)(Wg + col*CC + ks*32 + lg*8);
    }
    #pragma unroll
    for (int mt = 0; mt < 4; ++mt) {
      int arow = mt*16 + lr;
      s16x8 af[4];
      #pragma unroll
      for (int ks = 0; ks < 4; ++ks)
        af[ks] = *(const s16x8*)(XS + arow*CC + swzi(arow, ks*32 + lg*8));
      #pragma unroll
      for (int ntl = 0; ntl < 2; ++ntl) {
        f32x4 acc = {0.f, 0.f, 0.f, 0.f};
        #pragma unroll
        for (int ks = 0; ks < 4; ++ks)
          acc = __builtin_amdgcn_mfma_f32_16x16x32_bf16(af[ks], bfr[ntl][ks], acc, 0, 0, 0);
        int col = wv*32 + ntl*16 + lr;
        #pragma unroll
        for (int r = 0; r < 4; ++r) {
          int row = mt*16 + lg*4 + r;     // verified C/D mapping: row=(l>>4)*4+r, col=l&15
          if (row < NTOK) {
            unsigned short hv = f2bf(acc[r] + bb[ntl]);
            if (toVT) {
              int dd = col & 31;
              VT[(col >> 5)*(HDIM*64) + dd*64 + (row ^ ((dd & 7) << 3))] = hv;
            } else {
              dst[row*CC + swzi(row, col)] = hv;
            }
          }
        }
      }
    }
  };

  stage(Xq); __syncthreads();
  proj(Wbf, bq, Qs, 0); __syncthreads();
  stage(Xk); __syncthreads();
  proj(Wbf + 16384, bk, Ks, 0); __syncthreads();
  stage(Xv); __syncthreads();
  proj(Wbf + 32768, bv, VT, 1); __syncthreads();

  for (int h = 0; h < NHEADS; ++h) {
    { // S = q_h * k_h^T * scale + rel-pos bias ; one MFMA per 16x16 tile (K = HD = 32)
      int arow = wv*16 + lr;
      s16x8 aq = *(const s16x8*)(Qs + arow*CC + swzi(arow, h*HDIM + lg*8));
      #pragma unroll
      for (int nt = 0; nt < 4; ++nt) {
        int brow = nt*16 + lr;
        s16x8 bk8 = *(const s16x8*)(Ks + brow*CC + swzi(brow, h*HDIM + lg*8));
        f32x4 acc = {0.f, 0.f, 0.f, 0.f};
        acc = __builtin_amdgcn_mfma_f32_16x16x32_bf16(aq, bk8, acc, 0, 0, 0);
        #pragma unroll
        for (int r = 0; r < 4; ++r) {
          int row = wv*16 + lg*4 + r;
          int col = nt*16 + lr;
          if (row < NTOK && col < NTOK) {
            int i1 = row / 7, j1 = row - i1*7;
            int i2 = col / 7, j2 = col - i2*7;
            int ridx = (i1 - i2 + 6)*13 + (j1 - j2 + 6);
            Sm[row*65 + col] = acc[r] * SCALE_F + rpb[ridx*NHEADS + h];
          }
        }
      }
    }
    __syncthreads();
    if (tid < NTOK) { // row-per-lane softmax; stride 65 => conflict-free column reads
      int row = tid;
      float mx = -1e30f;
      for (int j = 0; j < NTOK; ++j) mx = fmaxf(mx, Sm[row*65 + j]);
      float sum = 0.f;
      for (int j = 0; j < NTOK; ++j) {
        float e = __expf(Sm[row*65 + j] - mx);
        sum += e;
        PB[row*64 + swzi(row, j)] = f2bf(e);   // unnormalized
      }
      SUMS[row] = 1.f / sum;
    }
    __syncthreads();
    { // out_h = P * V_h ; K=64 (2 steps), zero-padded in PB cols / VT toks
      int arow = wv*16 + lr;
      s16x8 pa[2];
      #pragma unroll
      for (int ks = 0; ks < 2; ++ks)
        pa[ks] = *(const s16x8*)(PB + arow*64 + swzi(arow, ks*32 + lg*8));
      #pragma unroll
      for (int nt = 0; nt < 2; ++nt) {
        int dd = nt*16 + lr;
        f32x4 acc = {0.f, 0.f, 0.f, 0.f};
        #pragma unroll
        for (int ks = 0; ks < 2; ++ks) {
          s16x8 bv8 = *(const s16x8*)(VT + h*(HDIM*64) + dd*64 + ((ks*32 + lg*8) ^ ((dd & 7) << 3)));
          acc = __builtin_amdgcn_mfma_f32_16x16x32_bf16(pa[ks], bv8, acc, 0, 0, 0);
        }
        #pragma unroll
        for (int r = 0; r < 4; ++r) {
          int row = wv*16 + lg*4 + r;
          if (row < NTOK) {
            int col = h*HDIM + nt*16 + lr;
            XS[row*CC + swzi(row, col)] = f2bf(acc[r] * SUMS[row]);
          }
        }
      }
    }
    { // ctx write: [win][h][49][49] fp32, coalesced across threads
      size_t cbase = ((size_t)win*NHEADS + h) * (NTOK*NTOK);
      for (int e = tid; e < NTOK*NTOK; e += 256) {
        int i = e / NTOK;
        out_ctx[cbase + e] = bf2f(PB[i*64 + swzi(i, e - i*NTOK)]) * SUMS[i];
      }
    }
    __syncthreads();
  }

  { // x = out @ Wo^T + bo, scatter to [B,C,H,W] fp32
    const unsigned short* Wg = Wbf + 49152;
    s16x8 bfr[2][4];
    float bb[2];
    #pragma unroll
    for (int ntl = 0; ntl < 2; ++ntl) {
      int col = wv*32 + ntl*16 + lr;
      bb[ntl] = bo[col];
      #pragma unroll
      for (int ks = 0; ks < 4; ++ks)
        bfr[ntl][ks] = *(const s16x8*)(Wg + col*CC + ks*32 + lg*8);
    }
    #pragma unroll
    for (int mt = 0; mt < 4; ++mt) {
      int arow = mt*16 + lr;
      s16x8 af[4];
      #pragma unroll
      for (int ks = 0; ks < 4; ++ks)
        af[ks] = *(const s16x8*)(XS + arow*CC + swzi(arow, ks*32 + lg*8));
      #pragma unroll
      for (int ntl = 0; ntl < 2; ++ntl) {
        f32x4 acc = {0.f, 0.f, 0.f, 0.f};
        #pragma unroll
        for (int ks = 0; ks < 4; ++ks)
          acc = __builtin_amdgcn_mfma_f32_16x16x32_bf16(af[ks], bfr[ntl][ks], acc, 0, 0, 0);
        int col = wv*32 + ntl*16 + lr;
        #pragma unroll
        for (int r = 0; r < 4; ++r) {
          int row = mt*16 + lg*4 + r;
          if (row < NTOK) {
            int ii = row / 7, jj = row - ii*7;
            size_t off = ((size_t)(bimg*CC + col))*HW2 + (size_t)(r0+ii)*HWW + (c0+jj);
            out_x[off] = acc[r] + bb[ntl];
          }
        }
      }
    }
  }
}

extern "C" void kernel_launch(void* const* d_in, const int* in_sizes, int n_in,
                              void* d_out, int out_size, void* d_ws, size_t ws_size,
                              hipStream_t stream) {
  (void)in_sizes; (void)n_in; (void)out_size; (void)ws_size;
  const float* query = (const float*)d_in[0];
  const float* key   = (const float*)d_in[1];
  const float* value = (const float*)d_in[2];
  const float* Wq = (const float*)d_in[3];
  const float* bq = (const float*)d_in[4];
  const float* Wk = (const float*)d_in[5];
  const float* bk = (const float*)d_in[6];
  const float* Wv = (const float*)d_in[7];
  const float* bv = (const float*)d_in[8];
  const float* Wo = (const float*)d_in[9];
  const float* bo = (const float*)d_in[10];
  const float* rpb = (const float*)d_in[11];

  unsigned short* Wbf = (unsigned short*)d_ws;           // 4 x [128][128] bf16 = 128 KB
  float* out_x   = (float*)d_out;                        // [64][128][56][56] fp32
  float* out_ctx = out_x + (size_t)64*CC*HW2;            // [4096][4][49][49] fp32

  wconv_kernel<<<256, 256, 0, stream>>>(Wq, Wk, Wv, Wo, Wbf);
  winattn_kernel<<<4096, 256, 0, stream>>>(query, key, value, Wbf, bq, bk, bv, bo, rpb,
                                           out_x, out_ctx);
}

// Round 3
// 383.623 us; speedup vs baseline: 1.1713x; 1.1713x over previous
//
#include <hip/hip_runtime.h>
#include <hip/hip_bf16.h>

#define NTOK 49
#define CC   128
#define HDIM 32
#define NHEADS 4
#define HWW  56
#define HW2  3136
#define SCALE_F 0.17677669529663687f

typedef __attribute__((ext_vector_type(8))) short s16x8;
typedef __attribute__((ext_vector_type(4))) float f32x4;

static __device__ __forceinline__ unsigned short f2bf(float f) {
  unsigned int u = __float_as_uint(f);
  u += 0x7fffu + ((u >> 16) & 1u);
  return (unsigned short)(u >> 16);
}
static __device__ __forceinline__ float bf2f(unsigned short h) {
  return __uint_as_float(((unsigned int)h) << 16);
}
// XOR swizzle on u16 index within a row: flips byte bits 4..6 -> keeps 16B alignment
static __device__ __forceinline__ int swzi(int row, int col) {
  return col ^ ((row & 7) << 3);
}

__global__ void wconv_kernel(const float* __restrict__ Wq, const float* __restrict__ Wk,
                             const float* __restrict__ Wv, const float* __restrict__ Wo,
                             unsigned short* __restrict__ dst) {
  int i = blockIdx.x * 256 + threadIdx.x;
  const float* src = (i < 16384) ? Wq : (i < 32768) ? Wk : (i < 49152) ? Wv : Wo;
  dst[i] = f2bf(src[i & 16383]);
}

__global__ __launch_bounds__(256, 2)
void winattn_kernel(const float* __restrict__ Xq, const float* __restrict__ Xk,
                    const float* __restrict__ Xv,
                    const unsigned short* __restrict__ Wbf,
                    const float* __restrict__ bq, const float* __restrict__ bk,
                    const float* __restrict__ bv, const float* __restrict__ bo,
                    const float* __restrict__ rpb,
                    float* __restrict__ out_x,
                    float* __restrict__ out_ctx)
{
  __shared__ alignas(16) unsigned char smem[75200];
  unsigned short* BufA = (unsigned short*)smem;        // [49][128] q-raw -> later K (projected)
  unsigned short* BufB = BufA + NTOK*CC;               // Q (projected)
  unsigned short* BufC = BufB + NTOK*CC;               // k-raw -> later attn-out
  unsigned short* VT = BufC + NTOK*CC;                 // [4][32][64] v^T per head, tok-swizzled by d
  unsigned short* PB = VT + NHEADS*HDIM*64;            // [64][64] unnormalized probs bf16, swizzled
  float* Sm   = (float*)(PB + 64*64);                  // [49][65] fp32 scores (phase-overlaid with v-raw)
  unsigned short* Vraw = (unsigned short*)Sm;          // [49][128] v-raw bf16 (12544B <= 12740B)
  float* SUMS = Sm + NTOK*65;                          // [49] 1/rowsum

  const int tid = threadIdx.x;
  const int wv  = tid >> 6;
  const int l   = tid & 63;
  const int lr  = l & 15;   // MFMA lane row/col
  const int lg  = l >> 4;   // MFMA k-group

  // XCD-bijective swizzle: 4096 blocks % 8 XCDs == 0 -> consecutive windows
  // (same 7-row band, shared cache lines) land on the SAME XCD's L2.
  const int win  = (blockIdx.x & 7) * 512 + (blockIdx.x >> 3);
  const int bimg = win >> 6;
  const int r0   = ((win >> 3) & 7) * 7;
  const int c0   = (win & 7) * 7;

  // ---- Phase 1: zero VT+PB padding, stage q,k,v in ONE pass (96 loads in flight)
  {
    unsigned int* z = (unsigned int*)VT;
    for (int i = tid; i < 6144; i += 256) z[i] = 0u;
  }
  {
    int s = tid & 63, g = tid >> 6;
    if (s < NTOK) {
      int si = s / 7, sj = s - si*7;
      size_t base = (size_t)bimg*CC*HW2 + (size_t)(r0+si)*HWW + (c0+sj);
      const float* pq = Xq + base;
      const float* pk = Xk + base;
      const float* pv = Xv + base;
      int rb = s * CC;
      #pragma unroll 16
      for (int cc = 0; cc < 32; ++cc) {
        int ci = g*32 + cc;
        size_t off = (size_t)ci * HW2;
        int di = rb + swzi(s, ci);
        BufA[di] = f2bf(pq[off]);
        BufC[di] = f2bf(pk[off]);
        Vraw[di] = f2bf(pv[off]);
      }
    }
  }
  __syncthreads();

  // D = src[49x128] * W^T + bias ; W row-major [co][ci] bf16; per-wave cols 32*wv..
  auto proj = [&](const unsigned short* __restrict__ src,
                  const unsigned short* __restrict__ Wg, const float* __restrict__ bias,
                  unsigned short* __restrict__ dst, int toVT) {
    s16x8 bfr[2][4];
    float bb[2];
    #pragma unroll
    for (int ntl = 0; ntl < 2; ++ntl) {
      int col = wv*32 + ntl*16 + lr;
      bb[ntl] = bias[col];
      #pragma unroll
      for (int ks = 0; ks < 4; ++ks)
        bfr[ntl][ks] = *(const s16x8*)(Wg + col*CC + ks*32 + lg*8);
    }
    #pragma unroll
    for (int mt = 0; mt < 4; ++mt) {
      int arow = mt*16 + lr;
      s16x8 af[4];
      #pragma unroll
      for (int ks = 0; ks < 4; ++ks)
        af[ks] = *(const s16x8*)(src + arow*CC + swzi(arow, ks*32 + lg*8));
      #pragma unroll
      for (int ntl = 0; ntl < 2; ++ntl) {
        f32x4 acc = {0.f, 0.f, 0.f, 0.f};
        #pragma unroll
        for (int ks = 0; ks < 4; ++ks)
          acc = __builtin_amdgcn_mfma_f32_16x16x32_bf16(af[ks], bfr[ntl][ks], acc, 0, 0, 0);
        int col = wv*32 + ntl*16 + lr;
        #pragma unroll
        for (int r = 0; r < 4; ++r) {
          int row = mt*16 + lg*4 + r;     // C/D mapping: row=(l>>4)*4+r, col=l&15
          if (row < NTOK) {
            unsigned short hv = f2bf(acc[r] + bb[ntl]);
            if (toVT) {
              int dd = col & 31;
              VT[(col >> 5)*(HDIM*64) + dd*64 + (row ^ ((dd & 7) << 3))] = hv;
            } else {
              dst[row*CC + swzi(row, col)] = hv;
            }
          }
        }
      }
    }
  };

  // ---- Phase 2: Q projection (reads BufA, writes BufB)
  proj(BufA, Wbf, bq, BufB, 0);
  __syncthreads();
  // ---- Phase 3: K projection (BufC -> BufA) and V projection (Vraw -> VT)
  proj(BufC, Wbf + 16384, bk, BufA, 0);
  proj(Vraw, Wbf + 32768, bv, nullptr, 1);
  __syncthreads();

  // Q = BufB, K = BufA, attn-out accumulates into BufC.
  auto qkt = [&](int h) {
    int arow = wv*16 + lr;
    s16x8 aq = *(const s16x8*)(BufB + arow*CC + swzi(arow, h*HDIM + lg*8));
    #pragma unroll
    for (int nt = 0; nt < 4; ++nt) {
      int brow = nt*16 + lr;
      s16x8 bk8 = *(const s16x8*)(BufA + brow*CC + swzi(brow, h*HDIM + lg*8));
      f32x4 acc = {0.f, 0.f, 0.f, 0.f};
      acc = __builtin_amdgcn_mfma_f32_16x16x32_bf16(aq, bk8, acc, 0, 0, 0);
      #pragma unroll
      for (int r = 0; r < 4; ++r) {
        int row = wv*16 + lg*4 + r;
        int col = nt*16 + lr;
        if (row < NTOK && col < NTOK) {
          int i1 = row / 7, j1 = row - i1*7;
          int i2 = col / 7, j2 = col - i2*7;
          int ridx = (i1 - i2 + 6)*13 + (j1 - j2 + 6);
          Sm[row*65 + col] = acc[r] * SCALE_F + rpb[ridx*NHEADS + h];
        }
      }
    }
  };

  auto softmax = [&]() { // 4 lanes per row, shfl-reduced; static vals[] indexing
    int R = wv*16 + (l >> 2);
    int q = l & 3;
    if (R < NTOK) {
      float vals[13];
      float mx = -1e30f;
      #pragma unroll
      for (int k = 0; k < 13; ++k) {
        int j = q + 4*k;
        float v = (j < NTOK) ? Sm[R*65 + j] : -1e30f;
        vals[k] = v;
        mx = fmaxf(mx, v);
      }
      mx = fmaxf(mx, __shfl_xor(mx, 1, 4));
      mx = fmaxf(mx, __shfl_xor(mx, 2, 4));
      float sum = 0.f;
      #pragma unroll
      for (int k = 0; k < 13; ++k) {
        int j = q + 4*k;
        float e = __expf(vals[k] - mx);   // j>=NTOK: exp(-huge)=0, harmless write below
        sum += e;
        if (j < 64) PB[R*64 + swzi(R, j)] = f2bf(e);
      }
      sum += __shfl_xor(sum, 1, 4);
      sum += __shfl_xor(sum, 2, 4);
      if (q == 0) SUMS[R] = 1.f / sum;
    }
  };

  auto pv = [&](int h) { // out_h = P * V_h ; K=64 (2 steps), zero-padded
    int arow = wv*16 + lr;
    s16x8 pa[2];
    #pragma unroll
    for (int ks = 0; ks < 2; ++ks)
      pa[ks] = *(const s16x8*)(PB + arow*64 + swzi(arow, ks*32 + lg*8));
    #pragma unroll
    for (int nt = 0; nt < 2; ++nt) {
      int dd = nt*16 + lr;
      f32x4 acc = {0.f, 0.f, 0.f, 0.f};
      #pragma unroll
      for (int ks = 0; ks < 2; ++ks) {
        s16x8 bv8 = *(const s16x8*)(VT + h*(HDIM*64) + dd*64 + ((ks*32 + lg*8) ^ ((dd & 7) << 3)));
        acc = __builtin_amdgcn_mfma_f32_16x16x32_bf16(pa[ks], bv8, acc, 0, 0, 0);
      }
      #pragma unroll
      for (int r = 0; r < 4; ++r) {
        int row = wv*16 + lg*4 + r;
        if (row < NTOK) {
          int col = h*HDIM + nt*16 + lr;
          BufC[row*CC + swzi(row, col)] = f2bf(acc[r] * SUMS[row]);
        }
      }
    }
  };

  auto ctxw = [&](int h) { // ctx write [win][h][49][49] fp32, coalesced
    size_t cbase = ((size_t)win*NHEADS + h) * (NTOK*NTOK);
    for (int e = tid; e < NTOK*NTOK; e += 256) {
      int i = e / NTOK;
      out_ctx[cbase + e] = bf2f(PB[i*64 + swzi(i, e - i*NTOK)]) * SUMS[i];
    }
  };

  // ---- Heads, software-pipelined: A_h = {QKT(h), PV(h-1), ctx(h-1)}, B_h = {softmax(h)}
  qkt(0);
  __syncthreads();
  softmax();
  __syncthreads();
  #pragma unroll
  for (int h = 1; h < NHEADS; ++h) {
    qkt(h);
    pv(h - 1);
    ctxw(h - 1);
    __syncthreads();
    softmax();
    __syncthreads();
  }
  pv(NHEADS - 1);
  ctxw(NHEADS - 1);
  __syncthreads();

  // ---- Output projection: x = attn_out @ Wo^T + bo, scatter to [B,C,H,W] fp32
  {
    const unsigned short* Wg = Wbf + 49152;
    s16x8 bfr[2][4];
    float bb[2];
    #pragma unroll
    for (int ntl = 0; ntl < 2; ++ntl) {
      int col = wv*32 + ntl*16 + lr;
      bb[ntl] = bo[col];
      #pragma unroll
      for (int ks = 0; ks < 4; ++ks)
        bfr[ntl][ks] = *(const s16x8*)(Wg + col*CC + ks*32 + lg*8);
    }
    #pragma unroll
    for (int mt = 0; mt < 4; ++mt) {
      int arow = mt*16 + lr;
      s16x8 af[4];
      #pragma unroll
      for (int ks = 0; ks < 4; ++ks)
        af[ks] = *(const s16x8*)(BufC + arow*CC + swzi(arow, ks*32 + lg*8));
      #pragma unroll
      for (int ntl = 0; ntl < 2; ++ntl) {
        f32x4 acc = {0.f, 0.f, 0.f, 0.f};
        #pragma unroll
        for (int ks = 0; ks < 4; ++ks)
          acc = __builtin_amdgcn_mfma_f32_16x16x32_bf16(af[ks], bfr[ntl][ks], acc, 0, 0, 0);
        int col = wv*32 + ntl*16 + lr;
        #pragma unroll
        for (int r = 0; r < 4; ++r) {
          int row = mt*16 + lg*4 + r;
          if (row < NTOK) {
            int ii = row / 7, jj = row - ii*7;
            size_t off = ((size_t)(bimg*CC + col))*HW2 + (size_t)(r0+ii)*HWW + (c0+jj);
            out_x[off] = acc[r] + bb[ntl];
          }
        }
      }
    }
  }
}

extern "C" void kernel_launch(void* const* d_in, const int* in_sizes, int n_in,
                              void* d_out, int out_size, void* d_ws, size_t ws_size,
                              hipStream_t stream) {
  (void)in_sizes; (void)n_in; (void)out_size; (void)ws_size;
  const float* query = (const float*)d_in[0];
  const float* key   = (const float*)d_in[1];
  const float* value = (const float*)d_in[2];
  const float* Wq = (const float*)d_in[3];
  const float* bq = (const float*)d_in[4];
  const float* Wk = (const float*)d_in[5];
  const float* bk = (const float*)d_in[6];
  const float* Wv = (const float*)d_in[7];
  const float* bv = (const float*)d_in[8];
  const float* Wo = (const float*)d_in[9];
  const float* bo = (const float*)d_in[10];
  const float* rpb = (const float*)d_in[11];

  unsigned short* Wbf = (unsigned short*)d_ws;           // 4 x [128][128] bf16 = 128 KB
  float* out_x   = (float*)d_out;                        // [64][128][56][56] fp32
  float* out_ctx = out_x + (size_t)64*CC*HW2;            // [4096][4][49][49] fp32

  wconv_kernel<<<256, 256, 0, stream>>>(Wq, Wk, Wv, Wo, Wbf);
  winattn_kernel<<<4096, 256, 0, stream>>>(query, key, value, Wbf, bq, bk, bv, bo, rpb,
                                           out_x, out_ctx);
}